// Round 7
// baseline (796.630 us; speedup 1.0000x reference)
//
#include <hip/hip_runtime.h>
#include <hip/hip_bf16.h>

// Problem constants
#define DM     128
#define DSTATE 16
#define DINNER 256
#define CCONV  16
#define NEIGH  27
#define DSEQ   432   // CCONV * NEIGH
#define DTRANK 14
#define LVOL   4096  // 16*16*16
#define BATCH  2
#define NTOK   8192  // BATCH * LVOL

typedef __attribute__((ext_vector_type(8))) unsigned short ushort8_t;

__device__ __forceinline__ float bf2f(unsigned short u) {
    union { unsigned int i; float f; } v; v.i = ((unsigned int)u) << 16; return v.f;
}

// ---------------------------------------------------------------- transposes
__global__ void k_transpose(const float* __restrict__ src, float* __restrict__ dst,
                            int rows, int cols) {
    int i = blockIdx.x * 256 + threadIdx.x;
    if (i < rows * cols) {
        int r = i / cols, c = i - r * cols;
        dst[c * rows + r] = src[i];
    }
}

// ---------------------------------------------------------------- in-proj GEMM
// xp -> channel-major xpt[(b*256+c)*4096 + l]; z -> token-major zbuf[tok*256 + c]
__global__ void k_inproj(const float* __restrict__ x, const float* __restrict__ w_in_t,
                         float* __restrict__ xpt, float* __restrict__ zbuf) {
    int t = threadIdx.x;
    int tokbase = blockIdx.x * 16;
    int b = tokbase >> 12, lb = tokbase & 4095;
    __shared__ float xs_[16][128];
    for (int idx = t; idx < 2048; idx += 256)
        xs_[idx >> 7][idx & 127] = x[tokbase * 128 + idx];
    __syncthreads();
    float a0[16], a1[16];
#pragma unroll
    for (int k = 0; k < 16; k++) { a0[k] = 0.f; a1[k] = 0.f; }
    for (int j = 0; j < 128; j++) {
        float w0 = w_in_t[j * 512 + t];
        float w1 = w_in_t[j * 512 + t + 256];
#pragma unroll
        for (int k = 0; k < 16; k++) {
            float xv = xs_[k][j];
            a0[k] += xv * w0;
            a1[k] += xv * w1;
        }
    }
    float* xr = xpt + (size_t)(b * 256 + t) * 4096 + lb;
#pragma unroll
    for (int k = 0; k < 16; k++) xr[k] = a0[k];
#pragma unroll
    for (int k = 0; k < 16; k++) zbuf[(tokbase + k) * 256 + t] = a1[k];
}

// ---------------------------------------------------------------- grouped conv3d + SiLU
__global__ void k_conv(const float* __restrict__ xpt, const float* __restrict__ conv_w,
                       const float* __restrict__ conv_b, float* __restrict__ xc) {
    int t = threadIdx.x;
    int tok = blockIdx.x * 256 + t;
    int co = blockIdx.y;
    int b = tok >> 12, l = tok & 4095;
    int d0 = l >> 8, h0 = (l >> 4) & 15, w0 = l & 15;
    __shared__ float wl[432];
    for (int i = t; i < 432; i += 256) wl[i] = conv_w[co * 432 + i];  // [q][27]
    __syncthreads();
    int nbo[27];
#pragma unroll
    for (int t27 = 0; t27 < 27; t27++) {
        int di = t27 / 9 - 1, dj = (t27 / 3) % 3 - 1, dk = t27 % 3 - 1;
        int zd = d0 + di, zh = h0 + dj, zw = w0 + dk;
        nbo[t27] = ((unsigned)zd > 15u || (unsigned)zh > 15u || (unsigned)zw > 15u)
                   ? -1 : ((zd << 8) + (zh << 4) + zw);
    }
    const float* xb = xpt + (size_t)(b * 256 + co * 16) * 4096;
    float acc0 = conv_b[co], acc1 = 0.f;
    for (int t27 = 0; t27 < 27; t27++) {
        int o = nbo[t27];
        if (o >= 0) {
#pragma unroll
            for (int q = 0; q < 16; q += 2) {
                acc0 += xb[q * 4096 + o]       * wl[q * 27 + t27];
                acc1 += xb[(q + 1) * 4096 + o] * wl[(q + 1) * 27 + t27];
            }
        }
    }
    float acc = acc0 + acc1;
    acc = acc / (1.f + __expf(-acc));  // SiLU
    xc[(b * 16 + co) * 4096 + l] = acc;
}

// ---------------------------------------------------------------- x_dbl = x_proj_w @ unfold(xc)
// c<14 -> dts[b][c][l] (fp32) ; c>=14 -> bc2[b][c-14][l] (bf16)
__global__ void k_xdbl(const float* __restrict__ xc, const float* __restrict__ x_proj_w,
                       float* __restrict__ dts, __hip_bfloat16* __restrict__ bc2) {
    int t = threadIdx.x;
    int tok = blockIdx.x * 256 + t;
    int c = blockIdx.y;  // 0..45
    int b = tok >> 12, l = tok & 4095;
    int d0 = l >> 8, h0 = (l >> 4) & 15, w0 = l & 15;
    __shared__ float wl[432];
    for (int i = t; i < 432; i += 256) wl[i] = x_proj_w[c * 432 + i];  // [ch][27]
    __syncthreads();
    int nbo[27];
#pragma unroll
    for (int t27 = 0; t27 < 27; t27++) {
        int di = t27 / 9 - 1, dj = (t27 / 3) % 3 - 1, dk = t27 % 3 - 1;
        int zd = d0 + di, zh = h0 + dj, zw = w0 + dk;
        nbo[t27] = ((unsigned)zd > 15u || (unsigned)zh > 15u || (unsigned)zw > 15u)
                   ? -1 : ((zd << 8) + (zh << 4) + zw);
    }
    const float* xcb = xc + b * 16 * 4096;
    float acc0 = 0.f, acc1 = 0.f;
    for (int t27 = 0; t27 < 27; t27++) {
        int o = nbo[t27];
        if (o >= 0) {
#pragma unroll
            for (int ch = 0; ch < 16; ch += 2) {
                acc0 += xcb[ch * 4096 + o]       * wl[ch * 27 + t27];
                acc1 += xcb[(ch + 1) * 4096 + o] * wl[(ch + 1) * 27 + t27];
            }
        }
    }
    float acc = acc0 + acc1;
    if (c < 14)
        dts[(size_t)(b * 14 + c) * 4096 + l] = acc;
    else
        bc2[(size_t)(b * 32 + (c - 14)) * 4096 + l] = __float2bfloat16(acc);
}

// ---------------------------------------------------------------- selective scan (+ fused delta)
// One block (512 thr) per (b, channel-pair). Thread t owns l in [t*8, t*8+8).
// G=2 channels (dch, dch+216) share the block's bc2/dts reads (L2 reuse).
// Pass 1 uses the suffix-sum form (no serial a-chain); pass 2 is the stable
// recurrence. B/C in bf16 (one 16B ushort8 load per 8-elem row).
__global__ __launch_bounds__(512, 2) void k_scan(
        const float* __restrict__ xc, const float* __restrict__ dts,
        const unsigned short* __restrict__ bc2, const float* __restrict__ dt_w,
        const float* __restrict__ dt_b, const float* __restrict__ A_logs,
        const float* __restrict__ Ds, float* __restrict__ y) {
    int bd = blockIdx.x;
    int b = bd / 216, cbase = bd % 216;
    int t = threadIdx.x;               // 0..511
    int lane = t & 63, wv = t >> 6;    // 8 waves

    __shared__ float waggA[8][16], waggB[8][16];

    const unsigned short* bcb = bc2 + (size_t)(b * 32) * 4096 + t * 8;
    const float* dsb = dts + (size_t)(b * 14) * 4096 + t * 8;

    // u-gather geometry (shared pieces)
    int d0 = t >> 5, h0 = (t >> 1) & 15, w0 = (t & 1) << 3;

    for (int g = 0; g < 2; g++) {
        int dch = cbase + g * 216;

        float A[16];
#pragma unroll
        for (int n = 0; n < 16; n++) A[n] = -__expf(A_logs[dch * 16 + n]);
        float Dskip = Ds[dch];

        int cch = dch / 27, t27 = dch % 27;
        int di = t27 / 9 - 1, dj = (t27 / 3) % 3 - 1, dk = t27 % 3 - 1;

        // ---- fused delta: softplus(sum_r dts[b][r][l]*dt_w[dch][r] + dt_b[dch])
        float dtv[8];
        {
            float s[8];
            float bias = dt_b[dch];
#pragma unroll
            for (int i = 0; i < 8; i++) s[i] = bias;
#pragma unroll
            for (int r = 0; r < 14; r++) {
                float d8[8];
                *(float4*)&d8[0] = *(const float4*)(dsb + (size_t)r * 4096);
                *(float4*)&d8[4] = *(const float4*)(dsb + (size_t)r * 4096 + 4);
                float w = dt_w[dch * 14 + r];
#pragma unroll
                for (int i = 0; i < 8; i++) s[i] += d8[i] * w;
            }
#pragma unroll
            for (int i = 0; i < 8; i++)
                dtv[i] = (s[i] > 15.f) ? s[i] : log1pf(__expf(s[i]));
        }

        // ---- u gather from l-major xc
        int zd = d0 + di, zh = h0 + dj;
        bool rowok = ((unsigned)zd <= 15u) && ((unsigned)zh <= 15u);
        const float* xr = xc + (size_t)(b * 16 + cch) * 4096 + (zd << 8) + (zh << 4);
        float uv[8], dtu[8];
#pragma unroll
        for (int i = 0; i < 8; i++) {
            int zw = w0 + i + dk;
            uv[i] = (rowok && (unsigned)zw <= 15u) ? xr[zw] : 0.f;
            dtu[i] = dtv[i] * uv[i];
        }

        // ---- suffix sums of dt (for pass-1 closed form)
        float suf[8];
        suf[7] = 0.f;
#pragma unroll
        for (int i = 6; i >= 0; i--) suf[i] = suf[i + 1] + dtv[i + 1];
        float tot = suf[0] + dtv[0];

        // ---- pass 1: chunk transform via suffix form (no serial chain)
        float Ap[16], Bp[16];
#pragma unroll
        for (int n = 0; n < 16; n++) {
            ushort8_t Bv = *(const ushort8_t*)(bcb + (size_t)n * 4096);
            float An = A[n];
            float bp = dtu[7] * bf2f(Bv[7]);   // e_7 = exp(0) = 1
#pragma unroll
            for (int i = 0; i < 7; i++)
                bp += __expf(An * suf[i]) * (dtu[i] * bf2f(Bv[i]));
            Ap[n] = __expf(An * tot);
            Bp[n] = bp;
        }

        // ---- wave-level inclusive scan (Hillis-Steele over 64 lanes)
#pragma unroll
        for (int s = 1; s < 64; s <<= 1) {
#pragma unroll
            for (int n = 0; n < 16; n++) {
                float pa = __shfl_up(Ap[n], s, 64);
                float pb = __shfl_up(Bp[n], s, 64);
                if (lane >= s) {
                    Bp[n] = Ap[n] * pb + Bp[n];
                    Ap[n] *= pa;
                }
            }
        }

        // ---- cross-wave prefix via tiny LDS
        __syncthreads();   // prior channel's readers done before overwrite
        if (lane == 63) {
#pragma unroll
            for (int n = 0; n < 16; n++) { waggA[wv][n] = Ap[n]; waggB[wv][n] = Bp[n]; }
        }
        __syncthreads();

        float h[16];
#pragma unroll
        for (int n = 0; n < 16; n++) {
            float exA = __shfl_up(Ap[n], 1, 64);
            float exB = __shfl_up(Bp[n], 1, 64);
            if (lane == 0) { exA = 1.f; exB = 0.f; }
            float WB = 0.f;
            for (int ww = 0; ww < wv; ww++)
                WB = waggA[ww][n] * WB + waggB[ww][n];
            h[n] = exA * WB + exB;     // incoming state for this chunk
        }

        // ---- pass 2: stable rescan; ys accumulators, bf16 B/C loads
        float ys[8];
#pragma unroll
        for (int i = 0; i < 8; i++) ys[i] = 0.f;
#pragma unroll
        for (int n = 0; n < 16; n++) {
            ushort8_t Bv = *(const ushort8_t*)(bcb + (size_t)n * 4096);
            ushort8_t Cv = *(const ushort8_t*)(bcb + (size_t)(16 + n) * 4096);
            float hn = h[n], An = A[n];
#pragma unroll
            for (int i = 0; i < 8; i++) {
                float a = __expf(dtv[i] * An);
                hn = a * hn + dtu[i] * bf2f(Bv[i]);
                ys[i] += hn * bf2f(Cv[i]);
            }
        }
        float* yo = y + (size_t)(b * 432 + dch) * 4096 + t * 8;
        float o8[8];
#pragma unroll
        for (int i = 0; i < 8; i++) o8[i] = ys[i] + Dskip * uv[i];
        *(float4*)(yo)     = *(float4*)&o8[0];
        *(float4*)(yo + 4) = *(float4*)&o8[4];
    }
}

// ---------------------------------------------------------------- fold GEMM + LN + gate + out GEMM
__global__ void k_tail(const float* __restrict__ y, const float* __restrict__ zbuf,
                       const float* __restrict__ wf_t, const float* __restrict__ ln_g,
                       const float* __restrict__ ln_b, const float* __restrict__ wo_t,
                       float* __restrict__ out) {
    int t = threadIdx.x;
    int tokbase = blockIdx.x * 16;
    int b = tokbase >> 12, lbase = tokbase & 4095;
    __shared__ float ys[432][16];
    __shared__ float vs[256][17];
    __shared__ float mu_s[16], rs_s[16];

    for (int idx = t; idx < 432 * 16; idx += 256) {
        int d = idx >> 4, tk = idx & 15;
        ys[d][tk] = y[(b * 432 + d) * 4096 + lbase + tk];
    }
    __syncthreads();

    float acc[16];
#pragma unroll
    for (int k = 0; k < 16; k++) acc[k] = 0.f;
    for (int d = 0; d < 432; d++) {
        float w = wf_t[d * 256 + t];
#pragma unroll
        for (int k = 0; k < 16; k++) acc[k] += w * ys[d][k];
    }
#pragma unroll
    for (int k = 0; k < 16; k++) vs[t][k] = acc[k];
    __syncthreads();

    {
        int tk = t >> 4, sub = t & 15;
        float s = 0.f, s2 = 0.f;
        for (int m = 0; m < 16; m++) {
            float v = vs[sub * 16 + m][tk];
            s += v; s2 += v * v;
        }
        s  += __shfl_xor(s, 1, 64);  s2 += __shfl_xor(s2, 1, 64);
        s  += __shfl_xor(s, 2, 64);  s2 += __shfl_xor(s2, 2, 64);
        s  += __shfl_xor(s, 4, 64);  s2 += __shfl_xor(s2, 4, 64);
        s  += __shfl_xor(s, 8, 64);  s2 += __shfl_xor(s2, 8, 64);
        if (sub == 0) {
            float mu = s * (1.f / 256.f);
            float var = s2 * (1.f / 256.f) - mu * mu;
            mu_s[tk] = mu;
            rs_s[tk] = rsqrtf(var + 1e-5f);
        }
    }
    __syncthreads();

    float g = ln_g[t], be = ln_b[t];
#pragma unroll
    for (int k = 0; k < 16; k++) {
        float zv = zbuf[(tokbase + k) * 256 + t];
        float sz = zv / (1.f + __expf(-zv));  // SiLU(z)
        vs[t][k] = ((acc[k] - mu_s[k]) * rs_s[k] * g + be) * sz;
    }
    __syncthreads();

    float oacc[8];
#pragma unroll
    for (int k = 0; k < 8; k++) oacc[k] = 0.f;
    int o = t & 127, kh = (t >> 7) * 8;
    for (int i = 0; i < 256; i++) {
        float w = wo_t[i * 128 + o];
#pragma unroll
        for (int k = 0; k < 8; k++) oacc[k] += w * vs[i][kh + k];
    }
#pragma unroll
    for (int k = 0; k < 8; k++)
        out[(tokbase + kh + k) * 128 + o] = oacc[k];
}

// ---------------------------------------------------------------- launch
extern "C" void kernel_launch(void* const* d_in, const int* in_sizes, int n_in,
                              void* d_out, int out_size, void* d_ws, size_t ws_size,
                              hipStream_t stream) {
    const float* x        = (const float*)d_in[0];
    const float* w_in     = (const float*)d_in[1];
    const float* conv_w   = (const float*)d_in[2];
    const float* conv_b   = (const float*)d_in[3];
    const float* x_proj_w = (const float*)d_in[4];
    const float* dt_w     = (const float*)d_in[5];
    const float* dt_b     = (const float*)d_in[6];
    const float* A_logs   = (const float*)d_in[7];
    const float* Ds       = (const float*)d_in[8];
    const float* w_fold   = (const float*)d_in[9];
    const float* ln_g     = (const float*)d_in[10];
    const float* ln_b     = (const float*)d_in[11];
    const float* w_out    = (const float*)d_in[12];
    float* out = (float*)d_out;

    float* ws     = (float*)d_ws;
    float* xpt    = ws;                    // B*256*L       = 2,097,152
    float* zbuf   = xpt    + 2097152;      // NTOK*256      = 2,097,152
    float* xc     = zbuf   + 2097152;      // B*16*L        =   131,072
    float* dts    = xc     + 131072;       // B*14*L        =   114,688
    float* bc2    = dts    + 114688;       // B*32*L bf16   (slot kept float-sized)
    float* ybuf   = bc2    + 262144;       // B*432*L       = 3,538,944
    float* wint   = ybuf   + 3538944;      // 512*128       =    65,536
    float* wft    = wint   + 65536;        // 432*256       =   110,592
    float* wot    = wft    + 110592;       // 256*128       =    32,768

    k_transpose<<<dim3((512 * 128 + 255) / 256), dim3(256), 0, stream>>>(w_in, wint, 512, 128);
    k_transpose<<<dim3((256 * 432 + 255) / 256), dim3(256), 0, stream>>>(w_fold, wft, 256, 432);
    k_transpose<<<dim3((128 * 256 + 255) / 256), dim3(256), 0, stream>>>(w_out, wot, 128, 256);

    k_inproj<<<dim3(NTOK / 16), dim3(256), 0, stream>>>(x, wint, xpt, zbuf);
    k_conv<<<dim3(NTOK / 256, CCONV), dim3(256), 0, stream>>>(xpt, conv_w, conv_b, xc);
    k_xdbl<<<dim3(NTOK / 256, 46), dim3(256), 0, stream>>>(xc, x_proj_w, dts, (__hip_bfloat16*)bc2);
    k_scan<<<dim3(BATCH * 216), dim3(512), 0, stream>>>(xc, dts, (const unsigned short*)bc2,
                                                        dt_w, dt_b, A_logs, Ds, ybuf);
    k_tail<<<dim3(NTOK / 16), dim3(256), 0, stream>>>(ybuf, zbuf, wft, ln_g, ln_b, wot, out);
}

// Round 8
// 775.705 us; speedup vs baseline: 1.0270x; 1.0270x over previous
//
#include <hip/hip_runtime.h>
#include <hip/hip_bf16.h>

// Problem constants
#define DM     128
#define DSTATE 16
#define DINNER 256
#define CCONV  16
#define NEIGH  27
#define DSEQ   432   // CCONV * NEIGH
#define DTRANK 14
#define LVOL   4096  // 16*16*16
#define BATCH  2
#define NTOK   8192  // BATCH * LVOL

typedef __attribute__((ext_vector_type(8))) unsigned short ushort8_t;

__device__ __forceinline__ float bf2f(unsigned short u) {
    union { unsigned int i; float f; } v; v.i = ((unsigned int)u) << 16; return v.f;
}

// ---------------------------------------------------------------- transposes
__global__ void k_transpose(const float* __restrict__ src, float* __restrict__ dst,
                            int rows, int cols) {
    int i = blockIdx.x * 256 + threadIdx.x;
    if (i < rows * cols) {
        int r = i / cols, c = i - r * cols;
        dst[c * rows + r] = src[i];
    }
}

// ---------------------------------------------------------------- in-proj GEMM
// xp -> channel-major xpt[(b*256+c)*4096 + l]; z -> token-major zbuf[tok*256 + c]
__global__ void k_inproj(const float* __restrict__ x, const float* __restrict__ w_in_t,
                         float* __restrict__ xpt, float* __restrict__ zbuf) {
    int t = threadIdx.x;
    int tokbase = blockIdx.x * 16;
    int b = tokbase >> 12, lb = tokbase & 4095;
    __shared__ float xs_[16][128];
    for (int idx = t; idx < 2048; idx += 256)
        xs_[idx >> 7][idx & 127] = x[tokbase * 128 + idx];
    __syncthreads();
    float a0[16], a1[16];
#pragma unroll
    for (int k = 0; k < 16; k++) { a0[k] = 0.f; a1[k] = 0.f; }
    for (int j = 0; j < 128; j++) {
        float w0 = w_in_t[j * 512 + t];
        float w1 = w_in_t[j * 512 + t + 256];
#pragma unroll
        for (int k = 0; k < 16; k++) {
            float xv = xs_[k][j];
            a0[k] += xv * w0;
            a1[k] += xv * w1;
        }
    }
    float* xr = xpt + (size_t)(b * 256 + t) * 4096 + lb;
#pragma unroll
    for (int k = 0; k < 16; k++) xr[k] = a0[k];
#pragma unroll
    for (int k = 0; k < 16; k++) zbuf[(tokbase + k) * 256 + t] = a1[k];
}

// ---------------------------------------------------------------- grouped conv3d + SiLU
__global__ void k_conv(const float* __restrict__ xpt, const float* __restrict__ conv_w,
                       const float* __restrict__ conv_b, float* __restrict__ xc) {
    int t = threadIdx.x;
    int tok = blockIdx.x * 256 + t;
    int co = blockIdx.y;
    int b = tok >> 12, l = tok & 4095;
    int d0 = l >> 8, h0 = (l >> 4) & 15, w0 = l & 15;
    __shared__ float wl[432];
    for (int i = t; i < 432; i += 256) wl[i] = conv_w[co * 432 + i];  // [q][27]
    __syncthreads();
    int nbo[27];
#pragma unroll
    for (int t27 = 0; t27 < 27; t27++) {
        int di = t27 / 9 - 1, dj = (t27 / 3) % 3 - 1, dk = t27 % 3 - 1;
        int zd = d0 + di, zh = h0 + dj, zw = w0 + dk;
        nbo[t27] = ((unsigned)zd > 15u || (unsigned)zh > 15u || (unsigned)zw > 15u)
                   ? -1 : ((zd << 8) + (zh << 4) + zw);
    }
    const float* xb = xpt + (size_t)(b * 256 + co * 16) * 4096;
    float acc0 = conv_b[co], acc1 = 0.f;
    for (int t27 = 0; t27 < 27; t27++) {
        int o = nbo[t27];
        if (o >= 0) {
#pragma unroll
            for (int q = 0; q < 16; q += 2) {
                acc0 += xb[q * 4096 + o]       * wl[q * 27 + t27];
                acc1 += xb[(q + 1) * 4096 + o] * wl[(q + 1) * 27 + t27];
            }
        }
    }
    float acc = acc0 + acc1;
    acc = acc / (1.f + __expf(-acc));  // SiLU
    xc[(b * 16 + co) * 4096 + l] = acc;
}

// ---------------------------------------------------------------- x_dbl = x_proj_w @ unfold(xc)
// c<14 -> dts[b][c][l] (fp32) ; c>=14 -> bc2[b][c-14][l] (bf16)
__global__ void k_xdbl(const float* __restrict__ xc, const float* __restrict__ x_proj_w,
                       float* __restrict__ dts, __hip_bfloat16* __restrict__ bc2) {
    int t = threadIdx.x;
    int tok = blockIdx.x * 256 + t;
    int c = blockIdx.y;  // 0..45
    int b = tok >> 12, l = tok & 4095;
    int d0 = l >> 8, h0 = (l >> 4) & 15, w0 = l & 15;
    __shared__ float wl[432];
    for (int i = t; i < 432; i += 256) wl[i] = x_proj_w[c * 432 + i];  // [ch][27]
    __syncthreads();
    int nbo[27];
#pragma unroll
    for (int t27 = 0; t27 < 27; t27++) {
        int di = t27 / 9 - 1, dj = (t27 / 3) % 3 - 1, dk = t27 % 3 - 1;
        int zd = d0 + di, zh = h0 + dj, zw = w0 + dk;
        nbo[t27] = ((unsigned)zd > 15u || (unsigned)zh > 15u || (unsigned)zw > 15u)
                   ? -1 : ((zd << 8) + (zh << 4) + zw);
    }
    const float* xcb = xc + b * 16 * 4096;
    float acc0 = 0.f, acc1 = 0.f;
    for (int t27 = 0; t27 < 27; t27++) {
        int o = nbo[t27];
        if (o >= 0) {
#pragma unroll
            for (int ch = 0; ch < 16; ch += 2) {
                acc0 += xcb[ch * 4096 + o]       * wl[ch * 27 + t27];
                acc1 += xcb[(ch + 1) * 4096 + o] * wl[(ch + 1) * 27 + t27];
            }
        }
    }
    float acc = acc0 + acc1;
    if (c < 14)
        dts[(size_t)(b * 14 + c) * 4096 + l] = acc;
    else
        bc2[(size_t)(b * 32 + (c - 14)) * 4096 + l] = __float2bfloat16(acc);
}

// ---------------------------------------------------------------- selective scan (+ fused delta)
// One block (512 thr) per (b, channel-pair). Thread t owns l in [t*8, t*8+8).
// G=2 channels (dch, dch+216) share the block's bc2/dts reads (L2 reuse).
// Pass 1 uses the suffix-sum form (no serial a-chain); pass 2 is the stable
// recurrence. B/C in bf16 (one 16B ushort8 load per 8-elem row).
__global__ __launch_bounds__(512, 2) void k_scan(
        const float* __restrict__ xc, const float* __restrict__ dts,
        const unsigned short* __restrict__ bc2, const float* __restrict__ dt_w,
        const float* __restrict__ dt_b, const float* __restrict__ A_logs,
        const float* __restrict__ Ds, float* __restrict__ y) {
    int bd = blockIdx.x;
    int b = bd / 216, cbase = bd % 216;
    int t = threadIdx.x;               // 0..511
    int lane = t & 63, wv = t >> 6;    // 8 waves

    __shared__ float waggA[8][16], waggB[8][16];

    const unsigned short* bcb = bc2 + (size_t)(b * 32) * 4096 + t * 8;
    const float* dsb = dts + (size_t)(b * 14) * 4096 + t * 8;

    // u-gather geometry (shared pieces)
    int d0 = t >> 5, h0 = (t >> 1) & 15, w0 = (t & 1) << 3;

    for (int g = 0; g < 2; g++) {
        int dch = cbase + g * 216;

        float A[16];
#pragma unroll
        for (int n = 0; n < 16; n++) A[n] = -__expf(A_logs[dch * 16 + n]);
        float Dskip = Ds[dch];

        int cch = dch / 27, t27 = dch % 27;
        int di = t27 / 9 - 1, dj = (t27 / 3) % 3 - 1, dk = t27 % 3 - 1;

        // ---- fused delta: softplus(sum_r dts[b][r][l]*dt_w[dch][r] + dt_b[dch])
        float dtv[8];
        {
            float s[8];
            float bias = dt_b[dch];
#pragma unroll
            for (int i = 0; i < 8; i++) s[i] = bias;
#pragma unroll
            for (int r = 0; r < 14; r++) {
                float d8[8];
                *(float4*)&d8[0] = *(const float4*)(dsb + (size_t)r * 4096);
                *(float4*)&d8[4] = *(const float4*)(dsb + (size_t)r * 4096 + 4);
                float w = dt_w[dch * 14 + r];
#pragma unroll
                for (int i = 0; i < 8; i++) s[i] += d8[i] * w;
            }
#pragma unroll
            for (int i = 0; i < 8; i++)
                dtv[i] = (s[i] > 15.f) ? s[i] : log1pf(__expf(s[i]));
        }

        // ---- u gather from l-major xc
        int zd = d0 + di, zh = h0 + dj;
        bool rowok = ((unsigned)zd <= 15u) && ((unsigned)zh <= 15u);
        const float* xr = xc + (size_t)(b * 16 + cch) * 4096 + (zd << 8) + (zh << 4);
        float uv[8], dtu[8];
#pragma unroll
        for (int i = 0; i < 8; i++) {
            int zw = w0 + i + dk;
            uv[i] = (rowok && (unsigned)zw <= 15u) ? xr[zw] : 0.f;
            dtu[i] = dtv[i] * uv[i];
        }

        // ---- suffix sums of dt (for pass-1 closed form)
        float suf[8];
        suf[7] = 0.f;
#pragma unroll
        for (int i = 6; i >= 0; i--) suf[i] = suf[i + 1] + dtv[i + 1];
        float tot = suf[0] + dtv[0];

        // ---- pass 1: chunk transform via suffix form (no serial chain)
        float Ap[16], Bp[16];
#pragma unroll
        for (int n = 0; n < 16; n++) {
            ushort8_t Bv = *(const ushort8_t*)(bcb + (size_t)n * 4096);
            float An = A[n];
            float bp = dtu[7] * bf2f(Bv[7]);   // e_7 = exp(0) = 1
#pragma unroll
            for (int i = 0; i < 7; i++)
                bp += __expf(An * suf[i]) * (dtu[i] * bf2f(Bv[i]));
            Ap[n] = __expf(An * tot);
            Bp[n] = bp;
        }

        // ---- wave-level inclusive scan (Hillis-Steele over 64 lanes)
#pragma unroll
        for (int s = 1; s < 64; s <<= 1) {
#pragma unroll
            for (int n = 0; n < 16; n++) {
                float pa = __shfl_up(Ap[n], s, 64);
                float pb = __shfl_up(Bp[n], s, 64);
                if (lane >= s) {
                    Bp[n] = Ap[n] * pb + Bp[n];
                    Ap[n] *= pa;
                }
            }
        }

        // ---- cross-wave prefix via tiny LDS
        __syncthreads();   // prior channel's readers done before overwrite
        if (lane == 63) {
#pragma unroll
            for (int n = 0; n < 16; n++) { waggA[wv][n] = Ap[n]; waggB[wv][n] = Bp[n]; }
        }
        __syncthreads();

        float h[16];
#pragma unroll
        for (int n = 0; n < 16; n++) {
            float exA = __shfl_up(Ap[n], 1, 64);
            float exB = __shfl_up(Bp[n], 1, 64);
            if (lane == 0) { exA = 1.f; exB = 0.f; }
            float WB = 0.f;
            for (int ww = 0; ww < wv; ww++)
                WB = waggA[ww][n] * WB + waggB[ww][n];
            h[n] = exA * WB + exB;     // incoming state for this chunk
        }

        // ---- pass 2: stable rescan; ys accumulators, bf16 B/C loads
        float ys[8];
#pragma unroll
        for (int i = 0; i < 8; i++) ys[i] = 0.f;
#pragma unroll
        for (int n = 0; n < 16; n++) {
            ushort8_t Bv = *(const ushort8_t*)(bcb + (size_t)n * 4096);
            ushort8_t Cv = *(const ushort8_t*)(bcb + (size_t)(16 + n) * 4096);
            float hn = h[n], An = A[n];
#pragma unroll
            for (int i = 0; i < 8; i++) {
                float a = __expf(dtv[i] * An);
                hn = a * hn + dtu[i] * bf2f(Bv[i]);
                ys[i] += hn * bf2f(Cv[i]);
            }
        }
        float* yo = y + (size_t)(b * 432 + dch) * 4096 + t * 8;
        float o8[8];
#pragma unroll
        for (int i = 0; i < 8; i++) o8[i] = ys[i] + Dskip * uv[i];
        *(float4*)(yo)     = *(float4*)&o8[0];
        *(float4*)(yo + 4) = *(float4*)&o8[4];
    }
}

// ---------------------------------------------------------------- fold GEMM + LN + gate + out GEMM
__global__ void k_tail(const float* __restrict__ y, const float* __restrict__ zbuf,
                       const float* __restrict__ wf_t, const float* __restrict__ ln_g,
                       const float* __restrict__ ln_b, const float* __restrict__ wo_t,
                       float* __restrict__ out) {
    int t = threadIdx.x;
    int tokbase = blockIdx.x * 16;
    int b = tokbase >> 12, lbase = tokbase & 4095;
    __shared__ float ys[432][16];
    __shared__ float vs[256][17];
    __shared__ float mu_s[16], rs_s[16];

    for (int idx = t; idx < 432 * 16; idx += 256) {
        int d = idx >> 4, tk = idx & 15;
        ys[d][tk] = y[(b * 432 + d) * 4096 + lbase + tk];
    }
    __syncthreads();

    float acc[16];
#pragma unroll
    for (int k = 0; k < 16; k++) acc[k] = 0.f;
    for (int d = 0; d < 432; d++) {
        float w = wf_t[d * 256 + t];
#pragma unroll
        for (int k = 0; k < 16; k++) acc[k] += w * ys[d][k];
    }
#pragma unroll
    for (int k = 0; k < 16; k++) vs[t][k] = acc[k];
    __syncthreads();

    {
        int tk = t >> 4, sub = t & 15;
        float s = 0.f, s2 = 0.f;
        for (int m = 0; m < 16; m++) {
            float v = vs[sub * 16 + m][tk];
            s += v; s2 += v * v;
        }
        s  += __shfl_xor(s, 1, 64);  s2 += __shfl_xor(s2, 1, 64);
        s  += __shfl_xor(s, 2, 64);  s2 += __shfl_xor(s2, 2, 64);
        s  += __shfl_xor(s, 4, 64);  s2 += __shfl_xor(s2, 4, 64);
        s  += __shfl_xor(s, 8, 64);  s2 += __shfl_xor(s2, 8, 64);
        if (sub == 0) {
            float mu = s * (1.f / 256.f);
            float var = s2 * (1.f / 256.f) - mu * mu;
            mu_s[tk] = mu;
            rs_s[tk] = rsqrtf(var + 1e-5f);
        }
    }
    __syncthreads();

    float g = ln_g[t], be = ln_b[t];
#pragma unroll
    for (int k = 0; k < 16; k++) {
        float zv = zbuf[(tokbase + k) * 256 + t];
        float sz = zv / (1.f + __expf(-zv));  // SiLU(z)
        vs[t][k] = ((acc[k] - mu_s[k]) * rs_s[k] * g + be) * sz;
    }
    __syncthreads();

    float oacc[8];
#pragma unroll
    for (int k = 0; k < 8; k++) oacc[k] = 0.f;
    int o = t & 127, kh = (t >> 7) * 8;
    for (int i = 0; i < 256; i++) {
        float w = wo_t[i * 128 + o];
#pragma unroll
        for (int k = 0; k < 8; k++) oacc[k] += w * vs[i][kh + k];
    }
#pragma unroll
    for (int k = 0; k < 8; k++)
        out[(tokbase + kh + k) * 128 + o] = oacc[k];
}

// ---------------------------------------------------------------- launch
extern "C" void kernel_launch(void* const* d_in, const int* in_sizes, int n_in,
                              void* d_out, int out_size, void* d_ws, size_t ws_size,
                              hipStream_t stream) {
    const float* x        = (const float*)d_in[0];
    const float* w_in     = (const float*)d_in[1];
    const float* conv_w   = (const float*)d_in[2];
    const float* conv_b   = (const float*)d_in[3];
    const float* x_proj_w = (const float*)d_in[4];
    const float* dt_w     = (const float*)d_in[5];
    const float* dt_b     = (const float*)d_in[6];
    const float* A_logs   = (const float*)d_in[7];
    const float* Ds       = (const float*)d_in[8];
    const float* w_fold   = (const float*)d_in[9];
    const float* ln_g     = (const float*)d_in[10];
    const float* ln_b     = (const float*)d_in[11];
    const float* w_out    = (const float*)d_in[12];
    float* out = (float*)d_out;

    float* ws     = (float*)d_ws;
    float* xpt    = ws;                    // B*256*L       = 2,097,152
    float* zbuf   = xpt    + 2097152;      // NTOK*256      = 2,097,152
    float* xc     = zbuf   + 2097152;      // B*16*L        =   131,072
    float* dts    = xc     + 131072;       // B*14*L        =   114,688
    float* bc2    = dts    + 114688;       // B*32*L bf16   (slot kept float-sized)
    float* ybuf   = bc2    + 262144;       // B*432*L       = 3,538,944
    float* wint   = ybuf   + 3538944;      // 512*128       =    65,536
    float* wft    = wint   + 65536;        // 432*256       =   110,592
    float* wot    = wft    + 110592;       // 256*128       =    32,768

    k_transpose<<<dim3((512 * 128 + 255) / 256), dim3(256), 0, stream>>>(w_in, wint, 512, 128);
    k_transpose<<<dim3((256 * 432 + 255) / 256), dim3(256), 0, stream>>>(w_fold, wft, 256, 432);
    k_transpose<<<dim3((128 * 256 + 255) / 256), dim3(256), 0, stream>>>(w_out, wot, 128, 256);

    k_inproj<<<dim3(NTOK / 16), dim3(256), 0, stream>>>(x, wint, xpt, zbuf);
    k_conv<<<dim3(NTOK / 256, CCONV), dim3(256), 0, stream>>>(xpt, conv_w, conv_b, xc);
    k_xdbl<<<dim3(NTOK / 256, 46), dim3(256), 0, stream>>>(xc, x_proj_w, dts, (__hip_bfloat16*)bc2);
    k_scan<<<dim3(BATCH * 216), dim3(512), 0, stream>>>(xc, dts, (const unsigned short*)bc2,
                                                        dt_w, dt_b, A_logs, Ds, ybuf);
    k_tail<<<dim3(NTOK / 16), dim3(256), 0, stream>>>(ybuf, zbuf, wft, ln_g, ln_b, wot, out);
}

// Round 9
// 217.015 us; speedup vs baseline: 3.6709x; 3.5744x over previous
//
#include <hip/hip_runtime.h>
#include <hip/hip_bf16.h>

// Problem constants
#define DM     128
#define DSTATE 16
#define DINNER 256
#define CCONV  16
#define NEIGH  27
#define DSEQ   432   // CCONV * NEIGH
#define DTRANK 14
#define LVOL   4096  // 16*16*16
#define BATCH  2
#define NTOK   8192  // BATCH * LVOL

typedef __attribute__((ext_vector_type(8))) unsigned short ushort8_t;

__device__ __forceinline__ float bf2f(unsigned short u) {
    union { unsigned int i; float f; } v; v.i = ((unsigned int)u) << 16; return v.f;
}

// ---------------------------------------------------------------- transposes
__global__ void k_transpose(const float* __restrict__ src, float* __restrict__ dst,
                            int rows, int cols) {
    int i = blockIdx.x * 256 + threadIdx.x;
    if (i < rows * cols) {
        int r = i / cols, c = i - r * cols;
        dst[c * rows + r] = src[i];
    }
}

// ---------------------------------------------------------------- in-proj GEMM
// xp -> channel-major xpt[(b*256+c)*4096 + l]; z -> token-major zbuf[tok*256 + c]
__global__ void k_inproj(const float* __restrict__ x, const float* __restrict__ w_in_t,
                         float* __restrict__ xpt, float* __restrict__ zbuf) {
    int t = threadIdx.x;
    int tokbase = blockIdx.x * 16;
    int b = tokbase >> 12, lb = tokbase & 4095;
    __shared__ float xs_[16][128];
    for (int idx = t; idx < 2048; idx += 256)
        xs_[idx >> 7][idx & 127] = x[tokbase * 128 + idx];
    __syncthreads();
    float a0[16], a1[16];
#pragma unroll
    for (int k = 0; k < 16; k++) { a0[k] = 0.f; a1[k] = 0.f; }
    for (int j = 0; j < 128; j++) {
        float w0 = w_in_t[j * 512 + t];
        float w1 = w_in_t[j * 512 + t + 256];
#pragma unroll
        for (int k = 0; k < 16; k++) {
            float xv = xs_[k][j];
            a0[k] += xv * w0;
            a1[k] += xv * w1;
        }
    }
    float* xr = xpt + (size_t)(b * 256 + t) * 4096 + lb;
#pragma unroll
    for (int k = 0; k < 16; k++) xr[k] = a0[k];
#pragma unroll
    for (int k = 0; k < 16; k++) zbuf[(tokbase + k) * 256 + t] = a1[k];
}

// ---------------------------------------------------------------- grouped conv3d + SiLU
__global__ void k_conv(const float* __restrict__ xpt, const float* __restrict__ conv_w,
                       const float* __restrict__ conv_b, float* __restrict__ xc) {
    int t = threadIdx.x;
    int tok = blockIdx.x * 256 + t;
    int co = blockIdx.y;
    int b = tok >> 12, l = tok & 4095;
    int d0 = l >> 8, h0 = (l >> 4) & 15, w0 = l & 15;
    __shared__ float wl[432];
    for (int i = t; i < 432; i += 256) wl[i] = conv_w[co * 432 + i];  // [q][27]
    __syncthreads();
    int nbo[27];
#pragma unroll
    for (int t27 = 0; t27 < 27; t27++) {
        int di = t27 / 9 - 1, dj = (t27 / 3) % 3 - 1, dk = t27 % 3 - 1;
        int zd = d0 + di, zh = h0 + dj, zw = w0 + dk;
        nbo[t27] = ((unsigned)zd > 15u || (unsigned)zh > 15u || (unsigned)zw > 15u)
                   ? -1 : ((zd << 8) + (zh << 4) + zw);
    }
    const float* xb = xpt + (size_t)(b * 256 + co * 16) * 4096;
    float acc0 = conv_b[co], acc1 = 0.f;
    for (int t27 = 0; t27 < 27; t27++) {
        int o = nbo[t27];
        if (o >= 0) {
#pragma unroll
            for (int q = 0; q < 16; q += 2) {
                acc0 += xb[q * 4096 + o]       * wl[q * 27 + t27];
                acc1 += xb[(q + 1) * 4096 + o] * wl[(q + 1) * 27 + t27];
            }
        }
    }
    float acc = acc0 + acc1;
    acc = acc / (1.f + __expf(-acc));  // SiLU
    xc[(b * 16 + co) * 4096 + l] = acc;
}

// ---------------------------------------------------------------- x_dbl = x_proj_w @ unfold(xc)
// c<14 -> dts[b][c][l] (fp32) ; c>=14 -> bc2[b][c-14][l] (bf16)
__global__ void k_xdbl(const float* __restrict__ xc, const float* __restrict__ x_proj_w,
                       float* __restrict__ dts, __hip_bfloat16* __restrict__ bc2) {
    int t = threadIdx.x;
    int tok = blockIdx.x * 256 + t;
    int c = blockIdx.y;  // 0..45
    int b = tok >> 12, l = tok & 4095;
    int d0 = l >> 8, h0 = (l >> 4) & 15, w0 = l & 15;
    __shared__ float wl[432];
    for (int i = t; i < 432; i += 256) wl[i] = x_proj_w[c * 432 + i];  // [ch][27]
    __syncthreads();
    int nbo[27];
#pragma unroll
    for (int t27 = 0; t27 < 27; t27++) {
        int di = t27 / 9 - 1, dj = (t27 / 3) % 3 - 1, dk = t27 % 3 - 1;
        int zd = d0 + di, zh = h0 + dj, zw = w0 + dk;
        nbo[t27] = ((unsigned)zd > 15u || (unsigned)zh > 15u || (unsigned)zw > 15u)
                   ? -1 : ((zd << 8) + (zh << 4) + zw);
    }
    const float* xcb = xc + b * 16 * 4096;
    float acc0 = 0.f, acc1 = 0.f;
    for (int t27 = 0; t27 < 27; t27++) {
        int o = nbo[t27];
        if (o >= 0) {
#pragma unroll
            for (int ch = 0; ch < 16; ch += 2) {
                acc0 += xcb[ch * 4096 + o]       * wl[ch * 27 + t27];
                acc1 += xcb[(ch + 1) * 4096 + o] * wl[(ch + 1) * 27 + t27];
            }
        }
    }
    float acc = acc0 + acc1;
    if (c < 14)
        dts[(size_t)(b * 14 + c) * 4096 + l] = acc;
    else
        bc2[(size_t)(b * 32 + (c - 14)) * 4096 + l] = __float2bfloat16(acc);
}

// ---------------------------------------------------------------- selective scan (+ fused delta)
// One block (512 thr) per (b, d-channel). Thread t owns l in [t*8, t*8+8).
// B/C in bf16 (one 16B ushort8 load per 8-elem row). A[n] = -(n+1) exactly
// (A_logs = log(1..16) broadcast), so exp(dt*A[n]) = exp(-dt)^(n+1): one exp
// per element + running multiply per state. Uniform runtime check with exact
// fallback keeps correctness independent of that assumption.
__global__ __launch_bounds__(512, 2) void k_scan(
        const float* __restrict__ xc, const float* __restrict__ dts,
        const unsigned short* __restrict__ bc2, const float* __restrict__ dt_w,
        const float* __restrict__ dt_b, const float* __restrict__ A_logs,
        const float* __restrict__ Ds, float* __restrict__ y) {
    int bd = blockIdx.x;
    int b = bd / 432, dch = bd % 432;
    int t = threadIdx.x;               // 0..511
    int lane = t & 63, wv = t >> 6;    // 8 waves

    float A[16];
    bool intA = true;
#pragma unroll
    for (int n = 0; n < 16; n++) {
        A[n] = -__expf(A_logs[dch * 16 + n]);
        intA = intA && (fabsf(A[n] + (float)(n + 1)) < 1e-3f);
    }
    float Dskip = Ds[dch];

    int cch = dch / 27, t27 = dch % 27;
    int di = t27 / 9 - 1, dj = (t27 / 3) % 3 - 1, dk = t27 % 3 - 1;

    // ---- fused delta: softplus(sum_r dts[b][r][l]*dt_w[dch][r] + dt_b[dch])
    float dtv[8];
    {
        float s[8];
        float bias = dt_b[dch];
#pragma unroll
        for (int i = 0; i < 8; i++) s[i] = bias;
        const float* dsb = dts + (size_t)(b * 14) * 4096 + t * 8;
#pragma unroll
        for (int r = 0; r < 14; r++) {
            float d8[8];
            *(float4*)&d8[0] = *(const float4*)(dsb + (size_t)r * 4096);
            *(float4*)&d8[4] = *(const float4*)(dsb + (size_t)r * 4096 + 4);
            float w = dt_w[dch * 14 + r];
#pragma unroll
            for (int i = 0; i < 8; i++) s[i] += d8[i] * w;
        }
#pragma unroll
        for (int i = 0; i < 8; i++)
            dtv[i] = (s[i] > 15.f) ? s[i] : log1pf(__expf(s[i]));
    }

    // ---- u gather from l-major xc (8 scalar loads, w-contiguous)
    int d0 = t >> 5, h0 = (t >> 1) & 15, w0 = (t & 1) << 3;
    int zd = d0 + di, zh = h0 + dj;
    bool rowok = ((unsigned)zd <= 15u) && ((unsigned)zh <= 15u);
    const float* xr = xc + (size_t)(b * 16 + cch) * 4096 + (zd << 8) + (zh << 4);
    float uv[8], dtu[8];
#pragma unroll
    for (int i = 0; i < 8; i++) {
        int zw = w0 + i + dk;
        uv[i] = (rowok && (unsigned)zw <= 15u) ? xr[zw] : 0.f;
        dtu[i] = dtv[i] * uv[i];
    }

    const unsigned short* bcb = bc2 + (size_t)(b * 32) * 4096 + t * 8;

    // ---- pass 1: chunk transform (Ap, Bp) per state
    float Ap[16], Bp[16];
    if (intA) {
        float av[8], aw[8];
#pragma unroll
        for (int i = 0; i < 8; i++) { av[i] = __expf(-dtv[i]); aw[i] = av[i]; }
        float P = ((av[0] * av[1]) * (av[2] * av[3])) * ((av[4] * av[5]) * (av[6] * av[7]));
        float ApAcc = P;
#pragma unroll
        for (int n = 0; n < 16; n++) {
            ushort8_t Bv = *(const ushort8_t*)(bcb + (size_t)n * 4096);
            float bp = 0.f;
#pragma unroll
            for (int i = 0; i < 8; i++)
                bp = aw[i] * bp + dtu[i] * bf2f(Bv[i]);
            Ap[n] = ApAcc; Bp[n] = bp;
            if (n < 15) {
#pragma unroll
                for (int i = 0; i < 8; i++) aw[i] *= av[i];
                ApAcc *= P;
            }
        }
    } else {
#pragma unroll
        for (int n = 0; n < 16; n++) {
            ushort8_t Bv = *(const ushort8_t*)(bcb + (size_t)n * 4096);
            float ap = 1.f, bp = 0.f, An = A[n];
#pragma unroll
            for (int i = 0; i < 8; i++) {
                float a = __expf(dtv[i] * An);
                bp = a * bp + dtu[i] * bf2f(Bv[i]);
                ap *= a;
            }
            Ap[n] = ap; Bp[n] = bp;
        }
    }

    // ---- wave-level inclusive scan (Hillis-Steele over 64 lanes)
#pragma unroll
    for (int s = 1; s < 64; s <<= 1) {
#pragma unroll
        for (int n = 0; n < 16; n++) {
            float pa = __shfl_up(Ap[n], s, 64);
            float pb = __shfl_up(Bp[n], s, 64);
            if (lane >= s) {
                Bp[n] = Ap[n] * pb + Bp[n];   // combine(earlier=(pa,pb), later)
                Ap[n] *= pa;
            }
        }
    }

    // ---- cross-wave prefix via tiny LDS
    __shared__ float waggA[8][16], waggB[8][16];
    if (lane == 63) {
#pragma unroll
        for (int n = 0; n < 16; n++) { waggA[wv][n] = Ap[n]; waggB[wv][n] = Bp[n]; }
    }
    __syncthreads();

    float h[16];
#pragma unroll
    for (int n = 0; n < 16; n++) {
        float exA = __shfl_up(Ap[n], 1, 64);
        float exB = __shfl_up(Bp[n], 1, 64);
        if (lane == 0) { exA = 1.f; exB = 0.f; }
        float WB = 0.f;
        for (int ww = 0; ww < wv; ww++)
            WB = waggA[ww][n] * WB + waggB[ww][n];
        h[n] = exA * WB + exB;     // incoming state for this chunk
    }

    // ---- pass 2: rescan with incoming state; ys accumulators
    float ys[8];
#pragma unroll
    for (int i = 0; i < 8; i++) ys[i] = 0.f;
    if (intA) {
        float av[8], aw[8];
#pragma unroll
        for (int i = 0; i < 8; i++) { av[i] = __expf(-dtv[i]); aw[i] = av[i]; }
#pragma unroll
        for (int n = 0; n < 16; n++) {
            ushort8_t Bv = *(const ushort8_t*)(bcb + (size_t)n * 4096);
            ushort8_t Cv = *(const ushort8_t*)(bcb + (size_t)(16 + n) * 4096);
            float hn = h[n];
#pragma unroll
            for (int i = 0; i < 8; i++) {
                hn = aw[i] * hn + dtu[i] * bf2f(Bv[i]);
                ys[i] += hn * bf2f(Cv[i]);
            }
            if (n < 15) {
#pragma unroll
                for (int i = 0; i < 8; i++) aw[i] *= av[i];
            }
        }
    } else {
#pragma unroll
        for (int n = 0; n < 16; n++) {
            ushort8_t Bv = *(const ushort8_t*)(bcb + (size_t)n * 4096);
            ushort8_t Cv = *(const ushort8_t*)(bcb + (size_t)(16 + n) * 4096);
            float hn = h[n], An = A[n];
#pragma unroll
            for (int i = 0; i < 8; i++) {
                float a = __expf(dtv[i] * An);
                hn = a * hn + dtu[i] * bf2f(Bv[i]);
                ys[i] += hn * bf2f(Cv[i]);
            }
        }
    }

    float* yo = y + (size_t)(b * 432 + dch) * 4096 + t * 8;
    float o8[8];
#pragma unroll
    for (int i = 0; i < 8; i++) o8[i] = ys[i] + Dskip * uv[i];
    *(float4*)(yo)     = *(float4*)&o8[0];
    *(float4*)(yo + 4) = *(float4*)&o8[4];
}

// ---------------------------------------------------------------- fold GEMM + LN + gate + out GEMM
__global__ void k_tail(const float* __restrict__ y, const float* __restrict__ zbuf,
                       const float* __restrict__ wf_t, const float* __restrict__ ln_g,
                       const float* __restrict__ ln_b, const float* __restrict__ wo_t,
                       float* __restrict__ out) {
    int t = threadIdx.x;
    int tokbase = blockIdx.x * 16;
    int b = tokbase >> 12, lbase = tokbase & 4095;
    __shared__ float ys[432][16];
    __shared__ float vs[256][17];
    __shared__ float mu_s[16], rs_s[16];

    for (int idx = t; idx < 432 * 16; idx += 256) {
        int d = idx >> 4, tk = idx & 15;
        ys[d][tk] = y[(b * 432 + d) * 4096 + lbase + tk];
    }
    __syncthreads();

    float acc[16];
#pragma unroll
    for (int k = 0; k < 16; k++) acc[k] = 0.f;
    for (int d = 0; d < 432; d++) {
        float w = wf_t[d * 256 + t];
#pragma unroll
        for (int k = 0; k < 16; k++) acc[k] += w * ys[d][k];
    }
#pragma unroll
    for (int k = 0; k < 16; k++) vs[t][k] = acc[k];
    __syncthreads();

    {
        int tk = t >> 4, sub = t & 15;
        float s = 0.f, s2 = 0.f;
        for (int m = 0; m < 16; m++) {
            float v = vs[sub * 16 + m][tk];
            s += v; s2 += v * v;
        }
        s  += __shfl_xor(s, 1, 64);  s2 += __shfl_xor(s2, 1, 64);
        s  += __shfl_xor(s, 2, 64);  s2 += __shfl_xor(s2, 2, 64);
        s  += __shfl_xor(s, 4, 64);  s2 += __shfl_xor(s2, 4, 64);
        s  += __shfl_xor(s, 8, 64);  s2 += __shfl_xor(s2, 8, 64);
        if (sub == 0) {
            float mu = s * (1.f / 256.f);
            float var = s2 * (1.f / 256.f) - mu * mu;
            mu_s[tk] = mu;
            rs_s[tk] = rsqrtf(var + 1e-5f);
        }
    }
    __syncthreads();

    float g = ln_g[t], be = ln_b[t];
#pragma unroll
    for (int k = 0; k < 16; k++) {
        float zv = zbuf[(tokbase + k) * 256 + t];
        float sz = zv / (1.f + __expf(-zv));  // SiLU(z)
        vs[t][k] = ((acc[k] - mu_s[k]) * rs_s[k] * g + be) * sz;
    }
    __syncthreads();

    float oacc[8];
#pragma unroll
    for (int k = 0; k < 8; k++) oacc[k] = 0.f;
    int o = t & 127, kh = (t >> 7) * 8;
    for (int i = 0; i < 256; i++) {
        float w = wo_t[i * 128 + o];
#pragma unroll
        for (int k = 0; k < 8; k++) oacc[k] += w * vs[i][kh + k];
    }
#pragma unroll
    for (int k = 0; k < 8; k++)
        out[(tokbase + kh + k) * 128 + o] = oacc[k];
}

// ---------------------------------------------------------------- launch
extern "C" void kernel_launch(void* const* d_in, const int* in_sizes, int n_in,
                              void* d_out, int out_size, void* d_ws, size_t ws_size,
                              hipStream_t stream) {
    const float* x        = (const float*)d_in[0];
    const float* w_in     = (const float*)d_in[1];
    const float* conv_w   = (const float*)d_in[2];
    const float* conv_b   = (const float*)d_in[3];
    const float* x_proj_w = (const float*)d_in[4];
    const float* dt_w     = (const float*)d_in[5];
    const float* dt_b     = (const float*)d_in[6];
    const float* A_logs   = (const float*)d_in[7];
    const float* Ds       = (const float*)d_in[8];
    const float* w_fold   = (const float*)d_in[9];
    const float* ln_g     = (const float*)d_in[10];
    const float* ln_b     = (const float*)d_in[11];
    const float* w_out    = (const float*)d_in[12];
    float* out = (float*)d_out;

    float* ws     = (float*)d_ws;
    float* xpt    = ws;                    // B*256*L       = 2,097,152
    float* zbuf   = xpt    + 2097152;      // NTOK*256      = 2,097,152
    float* xc     = zbuf   + 2097152;      // B*16*L        =   131,072
    float* dts    = xc     + 131072;       // B*14*L        =   114,688
    float* bc2    = dts    + 114688;       // B*32*L bf16   (slot kept float-sized)
    float* ybuf   = bc2    + 262144;       // B*432*L       = 3,538,944
    float* wint   = ybuf   + 3538944;      // 512*128       =    65,536
    float* wft    = wint   + 65536;        // 432*256       =   110,592
    float* wot    = wft    + 110592;       // 256*128       =    32,768

    k_transpose<<<dim3((512 * 128 + 255) / 256), dim3(256), 0, stream>>>(w_in, wint, 512, 128);
    k_transpose<<<dim3((256 * 432 + 255) / 256), dim3(256), 0, stream>>>(w_fold, wft, 256, 432);
    k_transpose<<<dim3((128 * 256 + 255) / 256), dim3(256), 0, stream>>>(w_out, wot, 128, 256);

    k_inproj<<<dim3(NTOK / 16), dim3(256), 0, stream>>>(x, wint, xpt, zbuf);
    k_conv<<<dim3(NTOK / 256, CCONV), dim3(256), 0, stream>>>(xpt, conv_w, conv_b, xc);
    k_xdbl<<<dim3(NTOK / 256, 46), dim3(256), 0, stream>>>(xc, x_proj_w, dts, (__hip_bfloat16*)bc2);
    k_scan<<<dim3(BATCH * DSEQ), dim3(512), 0, stream>>>(xc, dts, (const unsigned short*)bc2,
                                                         dt_w, dt_b, A_logs, Ds, ybuf);
    k_tail<<<dim3(NTOK / 16), dim3(256), 0, stream>>>(ybuf, zbuf, wft, ln_g, ln_b, wot, out);
}